// Round 4
// baseline (120.332 us; speedup 1.0000x reference)
//
#include <hip/hip_runtime.h>
#include <hip/hip_bf16.h>

typedef __bf16 bf16_t;
typedef __bf16 bf16x4 __attribute__((ext_vector_type(4)));
typedef __bf16 bf16x8 __attribute__((ext_vector_type(8)));
typedef float f32x4 __attribute__((ext_vector_type(4)));

#define M_TOT 8192
#define N_TOT 512
#define K_TOT 2048
#define E_TOT 512
#define NT    (K_TOT / 64)   // 32 K-tiles

// ---------------------------------------------------------------------------
// async global->LDS, 16B per lane. LDS dest = wave-uniform base + lane*16.
// ---------------------------------------------------------------------------
typedef const __attribute__((address_space(1))) void* gas_ptr;
typedef __attribute__((address_space(3))) void* las_ptr;

__device__ __forceinline__ void gload_lds16(const void* g, void* l) {
    __builtin_amdgcn_global_load_lds((gas_ptr)g, (las_ptr)l, 16, 0, 0);
}

__device__ __forceinline__ bf16x8 zero8() {
    bf16x8 v;
#pragma unroll
    for (int i = 0; i < 8; ++i) v[i] = (bf16_t)0.0f;
    return v;
}

// ---------------------------------------------------------------------------
// prep3 (unchanged from round 3; correctness-proven):
//  blocks [0,256):   LDS-tiled transpose W2[k][n] -> W2t[n][k] bf16
//  blocks [256,288): zb[m][0..8)=cos(theta[q])*cos(x[m,q]) (RX collapse),
//                    zb[m][8]=1 (bias lane), rest 0
//  blocks [288,296): W1t[f][0..8)=W1[q][f]; W1t[f][8]=b1[f]; rest 0
// ---------------------------------------------------------------------------
__global__ __launch_bounds__(256)
void prep3_kernel(const float* __restrict__ x,
                  const float* __restrict__ theta,
                  const float* __restrict__ W1,
                  const float* __restrict__ b1,
                  const float* __restrict__ W2,
                  bf16_t* __restrict__ W2t,
                  bf16_t* __restrict__ zb,
                  bf16_t* __restrict__ W1t)
{
    const int b = blockIdx.x;
    if (b < 256) {
        __shared__ bf16_t T[64][66];
        const int k0 = (b >> 3) * 64;
        const int n0 = (b & 7) * 64;
        const int kl = threadIdx.x >> 4;
        const int n4 = threadIdx.x & 15;
#pragma unroll
        for (int i = 0; i < 4; ++i) {
            int k = kl + i * 16;
            float4 v = *(const float4*)(W2 + (size_t)(k0 + k) * N_TOT + n0 + n4 * 4);
            T[n4 * 4 + 0][k] = (bf16_t)v.x;
            T[n4 * 4 + 1][k] = (bf16_t)v.y;
            T[n4 * 4 + 2][k] = (bf16_t)v.z;
            T[n4 * 4 + 3][k] = (bf16_t)v.w;
        }
        __syncthreads();
        const int nl = threadIdx.x >> 4;
        const int k4 = threadIdx.x & 15;
#pragma unroll
        for (int i = 0; i < 4; ++i) {
            int n = nl + i * 16;
            bf16x4 v;
            v[0] = T[n][k4 * 4 + 0];
            v[1] = T[n][k4 * 4 + 1];
            v[2] = T[n][k4 * 4 + 2];
            v[3] = T[n][k4 * 4 + 3];
            *(bf16x4*)(W2t + (size_t)(n0 + n) * K_TOT + k0 + k4 * 4) = v;
        }
    } else if (b < 288) {
        const int m = (b - 256) * 256 + threadIdx.x;
        float4 x0 = *(const float4*)(x + (size_t)m * E_TOT);
        float4 x1 = *(const float4*)(x + (size_t)m * E_TOT + 4);
        float xs[8] = {x0.x, x0.y, x0.z, x0.w, x1.x, x1.y, x1.z, x1.w};
        bf16x8 lo;
#pragma unroll
        for (int q = 0; q < 8; ++q)
            lo[q] = (bf16_t)(__builtin_cosf(theta[q]) * __builtin_cosf(xs[q]));
        bf16x8 hi = zero8();
        hi[0] = (bf16_t)1.0f;
        *(bf16x8*)(zb + (size_t)m * 16)     = lo;
        *(bf16x8*)(zb + (size_t)m * 16 + 8) = hi;
    } else {
        const int f = (b - 288) * 256 + threadIdx.x;
        bf16x8 lo;
#pragma unroll
        for (int q = 0; q < 8; ++q)
            lo[q] = (bf16_t)W1[(size_t)q * K_TOT + f];
        bf16x8 hi = zero8();
        hi[0] = (bf16_t)b1[f];
        *(bf16x8*)(W1t + (size_t)f * 16)     = lo;
        *(bf16x8*)(W1t + (size_t)f * 16 + 8) = hi;
    }
}

// ---------------------------------------------------------------------------
// Pipeline helpers
// ---------------------------------------------------------------------------
__device__ __forceinline__ void load_wf(const bf16_t* __restrict__ W1t, int k0,
                                        int l15, int lq, bf16x8 wf[4]) {
#pragma unroll
    for (int ft = 0; ft < 4; ++ft) wf[ft] = zero8();
    if (lq < 2) {
#pragma unroll
        for (int ft = 0; ft < 4; ++ft)
            wf[ft] = *(const bf16x8*)(W1t + (size_t)(k0 + ft * 16 + l15) * 16 + lq * 8);
    }
}

__device__ __forceinline__ void stage_B(const bf16_t* __restrict__ W2t, int n_base,
                                        int k0, bf16_t* Bb, int w, int lrow, int lseg) {
#pragma unroll
    for (int j = 0; j < 4; ++j) {
        int n = j * 32 + w * 8 + lrow;
        int g = lseg ^ (n & 7);
        gload_lds16(W2t + (size_t)(n_base + n) * K_TOT + k0 + g * 8,
                    Bb + j * 2048 + w * 512);
    }
}

// h tile via MFMA: h^T(f x m) = W1t(f x q+bias) @ z^T; relu -> swizzled Alds
__device__ __forceinline__ void h_stage(const bf16x8 wf[4], const bf16x8 zfrag[2],
                                        bf16_t* Ab, int w, int l15, int lq) {
#pragma unroll
    for (int mh = 0; mh < 2; ++mh) {
        int m_loc = w * 32 + mh * 16 + l15;
#pragma unroll
        for (int ft = 0; ft < 4; ++ft) {
            f32x4 hacc = (f32x4){0.f, 0.f, 0.f, 0.f};
            hacc = __builtin_amdgcn_mfma_f32_16x16x32_bf16(wf[ft], zfrag[mh], hacc, 0, 0, 0);
            bf16x4 hv;
#pragma unroll
            for (int r = 0; r < 4; ++r) hv[r] = (bf16_t)fmaxf(hacc[r], 0.f);
            int fseg = ft * 2 + (lq >> 1);        // f>>3
            int slot = fseg ^ (m_loc & 7);
            *(bf16x4*)(Ab + m_loc * 64 + slot * 8 + (lq & 1) * 4) = hv;
        }
    }
}

__device__ __forceinline__ void main_mfma(const bf16_t* Ab, const bf16_t* Bb,
                                          int wm, int wn, int l15, int lq,
                                          f32x4 acc[4][4]) {
#pragma unroll
    for (int kk = 0; kk < 2; ++kk) {
        bf16x8 af[4], bfr[4];
#pragma unroll
        for (int mt = 0; mt < 4; ++mt) {
            int r = wm * 64 + mt * 16 + l15;
            int s = (kk * 4 + lq) ^ (r & 7);
            af[mt] = *(const bf16x8*)(Ab + r * 64 + s * 8);
        }
#pragma unroll
        for (int nt = 0; nt < 4; ++nt) {
            int r = wn * 64 + nt * 16 + l15;
            int s = (kk * 4 + lq) ^ (r & 7);
            bfr[nt] = *(const bf16x8*)(Bb + r * 64 + s * 8);
        }
#pragma unroll
        for (int mt = 0; mt < 4; ++mt)
#pragma unroll
            for (int nt = 0; nt < 4; ++nt)
                acc[mt][nt] = __builtin_amdgcn_mfma_f32_16x16x32_bf16(
                    af[mt], bfr[nt], acc[mt][nt], 0, 0, 0);
    }
}

// ---------------------------------------------------------------------------
// Fused pipelined GEMM: out = relu(z@W1+b1) @ W2 + b2
// 128x128 tile, 4 waves of 64x64, A+B double-buffered (64KB LDS), grid 256.
// Tile i+1's gloads + h-MFMA writes go to buf[1-p] between the barrier that
// publishes buf[p] and the main MFMAs on buf[p] -> one-tile lookahead, the
// barrier's vmcnt(0) drain lands on already-complete loads.
// ---------------------------------------------------------------------------
__global__ __launch_bounds__(256)
void ffq_gemm_kernel(const bf16_t* __restrict__ zb,    // [8192][16]
                     const bf16_t* __restrict__ W1t,   // [2048][16]
                     const bf16_t* __restrict__ W2t,   // [512][2048]
                     const float* __restrict__ b2,
                     float* __restrict__ out)          // [8192][512]
{
    __shared__ bf16_t Alds[2][128 * 64];   // h tile  [m][slot = fseg ^ (m&7)]
    __shared__ bf16_t Blds[2][128 * 64];   // W2 tile [n][slot = kseg ^ (n&7)]

    const int t = threadIdx.x;
    const int w = t >> 6, l = t & 63;
    const int m_base = blockIdx.y * 128;
    const int n_base = blockIdx.x * 128;
    const int wm = w >> 1, wn = w & 1;
    const int l15 = l & 15, lq = l >> 4;
    const int lrow = l >> 3, lseg = l & 7;

    // persistent z^T B-frags: wave w owns h rows m_loc in [w*32, w*32+32)
    bf16x8 zfrag[2];
#pragma unroll
    for (int mh = 0; mh < 2; ++mh) {
        zfrag[mh] = zero8();
        if (lq < 2)
            zfrag[mh] = *(const bf16x8*)(zb + (size_t)(m_base + w * 32 + mh * 16 + l15) * 16 + lq * 8);
    }

    f32x4 acc[4][4];
#pragma unroll
    for (int mt = 0; mt < 4; ++mt)
#pragma unroll
        for (int nt = 0; nt < 4; ++nt)
            acc[mt][nt] = (f32x4){0.f, 0.f, 0.f, 0.f};

    // prologue: tile 0 -> buf 0
    {
        bf16x8 wf0[4];
        load_wf(W1t, 0, l15, lq, wf0);
        stage_B(W2t, n_base, 0, Blds[0], w, lrow, lseg);
        h_stage(wf0, zfrag, Alds[0], w, l15, lq);
    }

    for (int it = 0; it < NT; it += 2) {
        // ---- half A: publish buf0 (tile it), prefetch tile it+1 -> buf1 ----
        bf16x8 wfa[4];
        load_wf(W1t, (it + 1) * 64, l15, lq, wfa);   // drained by the barrier
        __syncthreads();
        stage_B(W2t, n_base, (it + 1) * 64, Blds[1], w, lrow, lseg);
        h_stage(wfa, zfrag, Alds[1], w, l15, lq);
        main_mfma(Alds[0], Blds[0], wm, wn, l15, lq, acc);

        // ---- half B: publish buf1 (tile it+1), prefetch tile it+2 -> buf0 ----
        bf16x8 wfb[4];
        if (it + 2 < NT) load_wf(W1t, (it + 2) * 64, l15, lq, wfb);
        __syncthreads();
        if (it + 2 < NT) {
            stage_B(W2t, n_base, (it + 2) * 64, Blds[0], w, lrow, lseg);
            h_stage(wfb, zfrag, Alds[0], w, l15, lq);
        }
        main_mfma(Alds[1], Blds[1], wm, wn, l15, lq, acc);
    }

    // ---- epilogue: C/D layout col=lane&15, row=(lane>>4)*4+r ----
#pragma unroll
    for (int nt = 0; nt < 4; ++nt) {
        int col = n_base + wn * 64 + nt * 16 + l15;
        float bias = b2[col];
#pragma unroll
        for (int mt = 0; mt < 4; ++mt) {
#pragma unroll
            for (int r = 0; r < 4; ++r) {
                int row = m_base + wm * 64 + mt * 16 + lq * 4 + r;
                out[(size_t)row * N_TOT + col] = acc[mt][nt][r] + bias;
            }
        }
    }
}

extern "C" void kernel_launch(void* const* d_in, const int* in_sizes, int n_in,
                              void* d_out, int out_size, void* d_ws, size_t ws_size,
                              hipStream_t stream) {
    const float* x     = (const float*)d_in[0];
    const float* theta = (const float*)d_in[1];
    const float* W1    = (const float*)d_in[2];
    const float* b1    = (const float*)d_in[3];
    const float* W2    = (const float*)d_in[4];
    const float* b2    = (const float*)d_in[5];
    float* out = (float*)d_out;

    // ws: [0,2MB) W2t ; [2MB,2.25MB) zb[8192][16] ; then W1t[2048][16]
    const size_t W2T_BYTES = (size_t)N_TOT * K_TOT * sizeof(bf16_t);  // 2 MB
    const size_t ZB_BYTES  = (size_t)M_TOT * 16 * sizeof(bf16_t);     // 256 KB

    bf16_t* W2t = (bf16_t*)d_ws;
    bf16_t* zb  = (bf16_t*)((char*)d_ws + W2T_BYTES);
    bf16_t* W1t = (bf16_t*)((char*)d_ws + W2T_BYTES + ZB_BYTES);

    prep3_kernel<<<296, 256, 0, stream>>>(x, theta, W1, b1, W2, W2t, zb, W1t);

    dim3 grid(N_TOT / 128, M_TOT / 128);   // (4, 64) = 256 blocks, 1/CU
    ffq_gemm_kernel<<<grid, 256, 0, stream>>>(zb, W1t, W2t, b2, out);
}